// Round 1
// baseline (483.990 us; speedup 1.0000x reference)
//
#include <hip/hip_runtime.h>
#include <stdint.h>

#define VOCAB 28996
#define EMBED 512
#define NROWS 8192
#define VPAD  29056  /* 227 * 128 */

typedef __attribute__((ext_vector_type(8))) __bf16 bf16x8;
typedef __attribute__((ext_vector_type(4))) float  f32x4;

__device__ __forceinline__ ushort f2bf(float f) {
  union { float f; uint32_t u; } c; c.f = f;
  return (ushort)((c.u + 0x7FFFu + ((c.u >> 16) & 1u)) >> 16);
}

__device__ __forceinline__ void gload_lds16(const void* g, void* l) {
  __builtin_amdgcn_global_load_lds(
      (__attribute__((address_space(1))) const void*)g,
      (__attribute__((address_space(3))) void*)l, 16, 0, 0);
}

// ---- convert x (fp32 -> bf16), 8192*512 elems, 4/thread ----
__global__ void cvt_x_kernel(const float* __restrict__ x, ushort* __restrict__ xb) {
  int i = (blockIdx.x * 256 + threadIdx.x) * 4;
  float4 v = *(const float4*)(x + i);
  ushort4 o;
  o.x = f2bf(v.x); o.y = f2bf(v.y); o.z = f2bf(v.z); o.w = f2bf(v.w);
  *(ushort4*)(xb + i) = o;
}

// ---- convert W (fp32 -> bf16) with zero-pad to VPAD rows ----
__global__ void cvt_w_kernel(const float* __restrict__ w, ushort* __restrict__ wb) {
  int i = (blockIdx.x * 256 + threadIdx.x) * 4;
  const int VK = VOCAB * EMBED;  // multiple of 4
  float4 v;
  if (i < VK) v = *(const float4*)(w + i);
  else { v.x = 0.f; v.y = 0.f; v.z = 0.f; v.w = 0.f; }
  ushort4 o;
  o.x = f2bf(v.x); o.y = f2bf(v.y); o.z = f2bf(v.z); o.w = f2bf(v.w);
  *(ushort4*)(wb + i) = o;
}

// ---- zero the row-stat accumulators (ws is poisoned 0xAA each launch) ----
__global__ void init_kernel(float* sg, float* qg, float* pyg) {
  int i = blockIdx.x * 256 + threadIdx.x;
  if (i < NROWS) { sg[i] = 0.f; qg[i] = 0.f; pyg[i] = 0.f; }
}

// ---- fused GEMM (logits = x . W^T + b) + softmax row-stats ----
// 128x128 tile, BK=64, 4 waves (2x2, each 64x64 of 16x16x32 MFMAs)
__global__ void __launch_bounds__(256, 2)
gemm_stats_kernel(const ushort* __restrict__ xb, const ushort* __restrict__ wb,
                  const float* __restrict__ bias, const int* __restrict__ y,
                  float* __restrict__ sg, float* __restrict__ qg,
                  float* __restrict__ pyg) {
  __shared__ ushort lA[128 * 64];
  __shared__ ushort lB[128 * 64];

  const int tid  = threadIdx.x;
  const int lane = tid & 63;
  const int w    = tid >> 6;       // wave 0..3
  const int quad = lane >> 4;      // 0..3
  const int lr   = lane & 15;      // 0..15
  const int wr   = (w >> 1) * 64;  // wave row offset in tile
  const int wc   = (w & 1) * 64;   // wave col offset in tile
  const int rowBase = blockIdx.x * 128;  // x rows (grid.x = 64)
  const int colBase = blockIdx.y * 128;  // vocab cols (grid.y = 227)

  f32x4 acc[4][4];
#pragma unroll
  for (int i = 0; i < 4; ++i) {
#pragma unroll
    for (int j = 0; j < 4; ++j) {
      f32x4 z = {0.f, 0.f, 0.f, 0.f};
      acc[i][j] = z;
    }
  }

  const int srow = lane >> 3;        // 0..7 (row within 8-row chunk)
  const int skel = (lane & 7) * 8;   // k-elem offset within 64

  for (int kt = 0; kt < 8; ++kt) {
    const int k0 = kt * 64;
    // stage A and B tiles: 16 chunks of 1KB each per tile, 4 chunks per wave
#pragma unroll
    for (int t = 0; t < 4; ++t) {
      const int c = w * 4 + t;          // chunk 0..15
      const int r = c * 8 + srow;       // tile row 0..127
      gload_lds16(xb + (size_t)(rowBase + r) * EMBED + k0 + skel, &lA[c * 512]);
      gload_lds16(wb + (size_t)(colBase + r) * EMBED + k0 + skel, &lB[c * 512]);
    }
    __syncthreads();  // compiler emits vmcnt(0) drain before barrier
#pragma unroll
    for (int kk = 0; kk < 2; ++kk) {
      const int ko = kk * 32 + quad * 8;
      bf16x8 af[4], bfr[4];
#pragma unroll
      for (int i = 0; i < 4; ++i)
        af[i] = *(const bf16x8*)&lA[(wr + i * 16 + lr) * 64 + ko];
#pragma unroll
      for (int j = 0; j < 4; ++j)
        bfr[j] = *(const bf16x8*)&lB[(wc + j * 16 + lr) * 64 + ko];
#pragma unroll
      for (int i = 0; i < 4; ++i) {
#pragma unroll
        for (int j = 0; j < 4; ++j)
          acc[i][j] = __builtin_amdgcn_mfma_f32_16x16x32_bf16(af[i], bfr[j], acc[i][j], 0, 0, 0);
      }
    }
    __syncthreads();
  }

  // ---- epilogue: e = exp(logit+bias); per-row s=sum e, q=sum e^2; catch e[y] ----
  // C/D layout (16x16x32): col = lane&15, row = quad*4 + reg
  int   cols[4];
  float bv[4], vmask[4];
#pragma unroll
  for (int j = 0; j < 4; ++j) {
    cols[j] = colBase + wc + j * 16 + lr;
    const bool valid = cols[j] < VOCAB;
    vmask[j] = valid ? 1.f : 0.f;
    bv[j] = valid ? bias[cols[j]] : 0.f;
  }

  float sp[4][4], qp[4][4];
#pragma unroll
  for (int i = 0; i < 4; ++i) {
#pragma unroll
    for (int r = 0; r < 4; ++r) {
      const int row = rowBase + wr + i * 16 + quad * 4 + r;
      const int yr = y[row];
      float s_loc = 0.f, q_loc = 0.f;
#pragma unroll
      for (int j = 0; j < 4; ++j) {
        const float l = acc[i][j][r] + bv[j];
        const float e = __expf(l) * vmask[j];  // padded cols: acc=0,b=0 -> masked to 0
        s_loc += e;
        q_loc += e * e;
        if (cols[j] == yr) pyg[row] = e;  // unique writer grid-wide
      }
      sp[i][r] = s_loc;
      qp[i][r] = q_loc;
    }
  }

  // butterfly over the 16 lanes sharing each output row (xor 1,2,4,8 stays in-group)
#pragma unroll
  for (int m = 1; m < 16; m <<= 1) {
#pragma unroll
    for (int i = 0; i < 4; ++i) {
#pragma unroll
      for (int r = 0; r < 4; ++r) {
        sp[i][r] += __shfl_xor(sp[i][r], m);
        qp[i][r] += __shfl_xor(qp[i][r], m);
      }
    }
  }
  if (lr == 0) {
#pragma unroll
    for (int i = 0; i < 4; ++i) {
#pragma unroll
      for (int r = 0; r < 4; ++r) {
        const int row = rowBase + wr + i * 16 + quad * 4 + r;
        atomicAdd(&sg[row], sp[i][r]);
        atomicAdd(&qg[row], qp[i][r]);
      }
    }
  }
}

// ---- final: nll_i = log(V+1 + q/(2 s^2)) - py/s ; out = mean ----
// (sum_j exp(p_j) = V + sum p + sum p^2/2 + O(p^3), sum p = 1, p <= ~2e-4)
__global__ void finalize_kernel(const float* __restrict__ sg, const float* __restrict__ qg,
                                const float* __restrict__ pyg, float* __restrict__ out) {
  __shared__ float red[256];
  float a = 0.f;
  for (int i = threadIdx.x; i < NROWS; i += 256) {
    const float s = sg[i];
    const float lse = logf((float)(VOCAB + 1) + 0.5f * qg[i] / (s * s));
    a += lse - pyg[i] / s;
  }
  red[threadIdx.x] = a;
  __syncthreads();
  for (int st = 128; st > 0; st >>= 1) {
    if (threadIdx.x < st) red[threadIdx.x] += red[threadIdx.x + st];
    __syncthreads();
  }
  if (threadIdx.x == 0) out[0] = red[0] * (1.f / (float)NROWS);
}

extern "C" void kernel_launch(void* const* d_in, const int* in_sizes, int n_in,
                              void* d_out, int out_size, void* d_ws, size_t ws_size,
                              hipStream_t stream) {
  const float* x = (const float*)d_in[0];
  const int*   y = (const int*)d_in[1];
  const float* W = (const float*)d_in[2];
  const float* b = (const float*)d_in[3];

  char* ws = (char*)d_ws;
  ushort* xb = (ushort*)ws;                               // 8,388,608 B
  ushort* wb = (ushort*)(ws + 8388608);                   // 29,753,344 B
  float*  sg = (float*)(ws + 8388608 + 29753344);         // 32 KiB
  float*  qg = sg + NROWS;                                // 32 KiB
  float*  pyg = qg + NROWS;                               // 32 KiB

  cvt_x_kernel<<<4096, 256, 0, stream>>>(x, xb);          // 8192*512/4/256
  cvt_w_kernel<<<14528, 256, 0, stream>>>(W, wb);         // 29056*512/4/256
  init_kernel<<<32, 256, 0, stream>>>(sg, qg, pyg);
  gemm_stats_kernel<<<dim3(64, 227), 256, 0, stream>>>(xb, wb, b, y, sg, qg, pyg);
  finalize_kernel<<<1, 256, 0, stream>>>(sg, qg, pyg, (float*)d_out);
}

// Round 2
// 430.014 us; speedup vs baseline: 1.1255x; 1.1255x over previous
//
#include <hip/hip_runtime.h>
#include <stdint.h>

#define VOCAB 28996
#define EMBED 512
#define NROWS 8192
#define VPAD  29056  /* 227 * 128 */
#define LOG2E 1.4426950408889634f

typedef __attribute__((ext_vector_type(8))) __bf16 bf16x8;
typedef __attribute__((ext_vector_type(4))) float  f32x4;

__device__ __forceinline__ ushort f2bf(float f) {
  union { float f; uint32_t u; } c; c.f = f;
  return (ushort)((c.u + 0x7FFFu + ((c.u >> 16) & 1u)) >> 16);
}

__device__ __forceinline__ void gload_lds16(const void* g, void* l) {
  __builtin_amdgcn_global_load_lds(
      (__attribute__((address_space(1))) const void*)g,
      (__attribute__((address_space(3))) void*)l, 16, 0, 0);
}

// ---- convert x (fp32 -> bf16), 8192*512 elems, 4/thread ----
__global__ void cvt_x_kernel(const float* __restrict__ x, ushort* __restrict__ xb) {
  int i = (blockIdx.x * 256 + threadIdx.x) * 4;
  float4 v = *(const float4*)(x + i);
  ushort4 o;
  o.x = f2bf(v.x); o.y = f2bf(v.y); o.z = f2bf(v.z); o.w = f2bf(v.w);
  *(ushort4*)(xb + i) = o;
}

// ---- convert W (fp32 -> bf16) with zero-pad to VPAD rows ----
__global__ void cvt_w_kernel(const float* __restrict__ w, ushort* __restrict__ wb) {
  int i = (blockIdx.x * 256 + threadIdx.x) * 4;
  const int VK = VOCAB * EMBED;  // multiple of 4
  float4 v;
  if (i < VK) v = *(const float4*)(w + i);
  else { v.x = 0.f; v.y = 0.f; v.z = 0.f; v.w = 0.f; }
  ushort4 o;
  o.x = f2bf(v.x); o.y = f2bf(v.y); o.z = f2bf(v.z); o.w = f2bf(v.w);
  *(ushort4*)(wb + i) = o;
}

// ---- zero the row-sum accumulator (ws is poisoned 0xAA each launch) ----
__global__ void init_kernel(float* sg) {
  int i = blockIdx.x * 256 + threadIdx.x;
  if (i < NROWS) sg[i] = 0.f;
}

// ---- p_y numerator: e^{x[row].W[y[row]] + b[y[row]]}, fp32 exact, 1 wave/row ----
__global__ void py_kernel(const float* __restrict__ x, const float* __restrict__ W,
                          const float* __restrict__ b, const int* __restrict__ y,
                          float* __restrict__ py) {
  const int row  = (blockIdx.x * 256 + threadIdx.x) >> 6;
  const int lane = threadIdx.x & 63;
  const int yr = y[row];
  const float4* xr = (const float4*)(x + (size_t)row * EMBED);
  const float4* wr = (const float4*)(W + (size_t)yr * EMBED);
  float d = 0.f;
#pragma unroll
  for (int t = 0; t < 2; ++t) {
    float4 a = xr[lane * 2 + t], c = wr[lane * 2 + t];
    d += a.x * c.x + a.y * c.y + a.z * c.z + a.w * c.w;
  }
#pragma unroll
  for (int m = 1; m < 64; m <<= 1) d += __shfl_xor(d, m);
  if (lane == 0) py[row] = __expf(d + b[yr]);
}

// ---- fused GEMM (logits = x . W^T + b) + row-sum of exp(logit) ----
// 128x128 tile, BK=64, 4 waves (2x2, each 64x64 of 16x16x32 MFMAs)
__global__ void __launch_bounds__(256, 2)
gemm_stats_kernel(const ushort* __restrict__ xb, const ushort* __restrict__ wb,
                  const float* __restrict__ bias, float* __restrict__ sg) {
  __shared__ ushort lA[128 * 64];
  __shared__ ushort lB[128 * 64];

  const int tid  = threadIdx.x;
  const int lane = tid & 63;
  const int w    = tid >> 6;       // wave 0..3
  const int quad = lane >> 4;      // 0..3
  const int lr   = lane & 15;      // 0..15
  const int wr   = (w >> 1) * 64;  // wave row offset in tile
  const int wc   = (w & 1) * 64;   // wave col offset in tile
  const int rowBase = blockIdx.x * 128;  // x rows (grid.x = 64)
  const int colBase = blockIdx.y * 128;  // vocab cols (grid.y = 227)

  f32x4 acc[4][4];
#pragma unroll
  for (int i = 0; i < 4; ++i) {
#pragma unroll
    for (int j = 0; j < 4; ++j) {
      f32x4 z = {0.f, 0.f, 0.f, 0.f};
      acc[i][j] = z;
    }
  }

  const int srow = lane >> 3;        // 0..7 (row within 8-row chunk)
  const int skel = (lane & 7) * 8;   // k-elem offset within 64

  for (int kt = 0; kt < 8; ++kt) {
    const int k0 = kt * 64;
#pragma unroll
    for (int t = 0; t < 4; ++t) {
      const int c = w * 4 + t;          // chunk 0..15
      const int r = c * 8 + srow;       // tile row 0..127
      gload_lds16(xb + (size_t)(rowBase + r) * EMBED + k0 + skel, &lA[c * 512]);
      gload_lds16(wb + (size_t)(colBase + r) * EMBED + k0 + skel, &lB[c * 512]);
    }
    __syncthreads();
#pragma unroll
    for (int kk = 0; kk < 2; ++kk) {
      const int ko = kk * 32 + quad * 8;
      bf16x8 af[4], bfr[4];
#pragma unroll
      for (int i = 0; i < 4; ++i)
        af[i] = *(const bf16x8*)&lA[(wr + i * 16 + lr) * 64 + ko];
#pragma unroll
      for (int j = 0; j < 4; ++j)
        bfr[j] = *(const bf16x8*)&lB[(wc + j * 16 + lr) * 64 + ko];
#pragma unroll
      for (int i = 0; i < 4; ++i) {
#pragma unroll
        for (int j = 0; j < 4; ++j)
          acc[i][j] = __builtin_amdgcn_mfma_f32_16x16x32_bf16(af[i], bfr[j], acc[i][j], 0, 0, 0);
      }
    }
    __syncthreads();
  }

  // ---- epilogue: s_row += sum_j exp(logit+bias) ----
  // C/D layout (16x16x32): col = lane&15, row = quad*4 + reg
  // per logit: 1 fma (acc*log2e + bias*log2e) + 1 exp2 + 1 add; padded cols get -1e30 -> 0
  float bvl[4];
#pragma unroll
  for (int j = 0; j < 4; ++j) {
    const int col = colBase + wc + j * 16 + lr;
    bvl[j] = (col < VOCAB) ? bias[col] * LOG2E : -1e30f;
  }

  float sp[16];
#pragma unroll
  for (int i = 0; i < 4; ++i) {
#pragma unroll
    for (int r = 0; r < 4; ++r) {
      float s_loc = 0.f;
#pragma unroll
      for (int j = 0; j < 4; ++j)
        s_loc += exp2f(fmaf(acc[i][j][r], LOG2E, bvl[j]));
      sp[i * 4 + r] = s_loc;
    }
  }

  // stacking reduction over the 16 lanes of each quad-group:
  // ends with lane lr holding the full sum for reg index u == lr.
  float t1[8];
#pragma unroll
  for (int u = 0; u < 8; ++u) {
    float a = sp[2 * u]     + __shfl_xor(sp[2 * u],     1);
    float b = sp[2 * u + 1] + __shfl_xor(sp[2 * u + 1], 1);
    t1[u] = (lr & 1) ? b : a;
  }
  float t2[4];
#pragma unroll
  for (int u = 0; u < 4; ++u) {
    float a = t1[2 * u]     + __shfl_xor(t1[2 * u],     2);
    float b = t1[2 * u + 1] + __shfl_xor(t1[2 * u + 1], 2);
    t2[u] = (lr & 2) ? b : a;
  }
  float t3[2];
#pragma unroll
  for (int u = 0; u < 2; ++u) {
    float a = t2[2 * u]     + __shfl_xor(t2[2 * u],     4);
    float b = t2[2 * u + 1] + __shfl_xor(t2[2 * u + 1], 4);
    t3[u] = (lr & 4) ? b : a;
  }
  {
    float a = t3[0] + __shfl_xor(t3[0], 8);
    float b = t3[1] + __shfl_xor(t3[1], 8);
    float ssum = (lr & 8) ? b : a;
    // lane (quad, lr) holds row-sum for u = lr: row = wr + (u>>2)*16 + quad*4 + (u&3)
    const int row = rowBase + wr + (lr >> 2) * 16 + quad * 4 + (lr & 3);
    atomicAdd(&sg[row], ssum);
  }
}

// ---- final: loss = log(V+1) - mean(py/s)  (q-term ~7e-10, dropped) ----
__global__ void finalize_kernel(const float* __restrict__ sg, const float* __restrict__ py,
                                float* __restrict__ out) {
  __shared__ float red[256];
  float a = 0.f;
  for (int i = threadIdx.x; i < NROWS; i += 256)
    a += py[i] / sg[i];
  red[threadIdx.x] = a;
  __syncthreads();
  for (int st = 128; st > 0; st >>= 1) {
    if (threadIdx.x < st) red[threadIdx.x] += red[threadIdx.x + st];
    __syncthreads();
  }
  if (threadIdx.x == 0)
    out[0] = logf((float)(VOCAB + 1)) - red[0] * (1.f / (float)NROWS);
}

extern "C" void kernel_launch(void* const* d_in, const int* in_sizes, int n_in,
                              void* d_out, int out_size, void* d_ws, size_t ws_size,
                              hipStream_t stream) {
  const float* x = (const float*)d_in[0];
  const int*   y = (const int*)d_in[1];
  const float* W = (const float*)d_in[2];
  const float* b = (const float*)d_in[3];

  char* ws = (char*)d_ws;
  ushort* xb = (ushort*)ws;                               // 8,388,608 B
  ushort* wb = (ushort*)(ws + 8388608);                   // 29,753,344 B
  float*  sg = (float*)(ws + 8388608 + 29753344);         // 32 KiB
  float*  py = sg + NROWS;                                // 32 KiB

  cvt_x_kernel<<<4096, 256, 0, stream>>>(x, xb);
  cvt_w_kernel<<<14528, 256, 0, stream>>>(W, wb);
  init_kernel<<<32, 256, 0, stream>>>(sg);
  py_kernel<<<2048, 256, 0, stream>>>(x, W, b, y, py);
  gemm_stats_kernel<<<dim3(64, 227), 256, 0, stream>>>(xb, wb, b, sg);
  finalize_kernel<<<1, 256, 0, stream>>>(sg, py, (float*)d_out);
}

// Round 3
// 383.597 us; speedup vs baseline: 1.2617x; 1.1210x over previous
//
#include <hip/hip_runtime.h>
#include <stdint.h>

#define VOCAB 28996
#define EMBED 512
#define NROWS 8192
#define VPAD  29056  /* 227 * 128 */
#define LOG2E 1.4426950408889634f

typedef __attribute__((ext_vector_type(8))) __bf16 bf16x8;
typedef __attribute__((ext_vector_type(4))) float  f32x4;

__device__ __forceinline__ ushort f2bf(float f) {
  union { float f; uint32_t u; } c; c.f = f;
  return (ushort)((c.u + 0x7FFFu + ((c.u >> 16) & 1u)) >> 16);
}

__device__ __forceinline__ void gload_lds16(const void* g, void* l) {
  __builtin_amdgcn_global_load_lds(
      (__attribute__((address_space(1))) const void*)g,
      (__attribute__((address_space(3))) void*)l, 16, 0, 0);
}

// ---- fused prep: cvt W, cvt x, p_y numerator, zero sg — one launch ----
// blocks [0,14528): W fp32->bf16 (pad to VPAD rows)
// blocks [14528,18624): x fp32->bf16
// blocks [18624,20672): py (1 wave per row, 4 rows/block)
// blocks [20672,20704): zero sg
__global__ void __launch_bounds__(256)
prep_kernel(const float* __restrict__ x, const float* __restrict__ W,
            const float* __restrict__ b, const int* __restrict__ y,
            ushort* __restrict__ xb, ushort* __restrict__ wb,
            float* __restrict__ py, float* __restrict__ sg) {
  const int bid = blockIdx.x;
  if (bid < 14528) {                       // ---- cvt W ----
    int i = (bid * 256 + threadIdx.x) * 4;
    const int VK = VOCAB * EMBED;
    float4 v;
    if (i < VK) v = *(const float4*)(W + i);
    else { v.x = 0.f; v.y = 0.f; v.z = 0.f; v.w = 0.f; }
    ushort4 o;
    o.x = f2bf(v.x); o.y = f2bf(v.y); o.z = f2bf(v.z); o.w = f2bf(v.w);
    *(ushort4*)(wb + i) = o;
  } else if (bid < 18624) {                // ---- cvt x ----
    int i = ((bid - 14528) * 256 + threadIdx.x) * 4;
    float4 v = *(const float4*)(x + i);
    ushort4 o;
    o.x = f2bf(v.x); o.y = f2bf(v.y); o.z = f2bf(v.z); o.w = f2bf(v.w);
    *(ushort4*)(xb + i) = o;
  } else if (bid < 20672) {                // ---- py: e^{x.W[y]+b[y]}, fp32 ----
    const int row  = ((bid - 18624) * 256 + threadIdx.x) >> 6;
    const int lane = threadIdx.x & 63;
    const int yr = y[row];
    const float4* xr = (const float4*)(x + (size_t)row * EMBED);
    const float4* wr = (const float4*)(W + (size_t)yr * EMBED);
    float d = 0.f;
#pragma unroll
    for (int t = 0; t < 2; ++t) {
      float4 a = xr[lane * 2 + t], c = wr[lane * 2 + t];
      d += a.x * c.x + a.y * c.y + a.z * c.z + a.w * c.w;
    }
#pragma unroll
    for (int m = 1; m < 64; m <<= 1) d += __shfl_xor(d, m);
    if (lane == 0) py[row] = __expf(d + b[yr]);
  } else {                                 // ---- zero sg ----
    int i = (bid - 20672) * 256 + threadIdx.x;
    sg[i] = 0.f;
  }
}

// ---- fused GEMM (logits = x . W^T + b) + row-sum of exp(logit) ----
// 128x128 tile, BK=64, 4 waves (2x2, each 64x64 of 16x16x32 MFMAs).
// LDS k-chunk XOR swizzle: global k-chunk J of row R lives at
// LDS[R*64 + ((J ^ (R&7))*8)] — staging stays global_load_lds-contiguous,
// fragment reads become bank-conflict-free (was 8-way on the 128B row stride).
__global__ void __launch_bounds__(256, 2)
gemm_stats_kernel(const ushort* __restrict__ xb, const ushort* __restrict__ wb,
                  const float* __restrict__ bias, float* __restrict__ sg) {
  __shared__ ushort lA[128 * 64];
  __shared__ ushort lB[128 * 64];

  const int tid  = threadIdx.x;
  const int lane = tid & 63;
  const int w    = tid >> 6;       // wave 0..3
  const int quad = lane >> 4;      // 0..3
  const int lr   = lane & 15;      // 0..15
  const int kx   = lr & 7;         // swizzle key for fragment reads (row&7)
  const int wr   = (w >> 1) * 64;  // wave row offset in tile
  const int wc   = (w & 1) * 64;   // wave col offset in tile
  const int rowBase = blockIdx.x * 128;  // x rows (grid.x = 64)
  const int colBase = blockIdx.y * 128;  // vocab cols (grid.y = 227)

  f32x4 acc[4][4];
#pragma unroll
  for (int i = 0; i < 4; ++i) {
#pragma unroll
    for (int j = 0; j < 4; ++j) {
      f32x4 z = {0.f, 0.f, 0.f, 0.f};
      acc[i][j] = z;
    }
  }

  const int srow = lane >> 3;                       // 0..7
  const int skel = ((lane & 7) ^ srow) * 8;         // swizzled k-elem offset

  for (int kt = 0; kt < 8; ++kt) {
    const int k0 = kt * 64;
#pragma unroll
    for (int t = 0; t < 4; ++t) {
      const int c = w * 4 + t;          // chunk 0..15
      const int r = c * 8 + srow;       // tile row 0..127
      gload_lds16(xb + (size_t)(rowBase + r) * EMBED + k0 + skel, &lA[c * 512]);
      gload_lds16(wb + (size_t)(colBase + r) * EMBED + k0 + skel, &lB[c * 512]);
    }
    __syncthreads();
#pragma unroll
    for (int kk = 0; kk < 2; ++kk) {
      const int ko = ((kk * 4 + quad) ^ kx) * 8;    // swizzled fragment offset
      bf16x8 af[4], bfr[4];
#pragma unroll
      for (int i = 0; i < 4; ++i)
        af[i] = *(const bf16x8*)&lA[(wr + i * 16 + lr) * 64 + ko];
#pragma unroll
      for (int j = 0; j < 4; ++j)
        bfr[j] = *(const bf16x8*)&lB[(wc + j * 16 + lr) * 64 + ko];
#pragma unroll
      for (int i = 0; i < 4; ++i) {
#pragma unroll
        for (int j = 0; j < 4; ++j)
          acc[i][j] = __builtin_amdgcn_mfma_f32_16x16x32_bf16(af[i], bfr[j], acc[i][j], 0, 0, 0);
      }
    }
    __syncthreads();
  }

  // ---- epilogue: s_row += sum_j exp(logit+bias) ----
  // C/D layout (16x16x32): col = lane&15, row = quad*4 + reg
  float bvl[4];
#pragma unroll
  for (int j = 0; j < 4; ++j) {
    const int col = colBase + wc + j * 16 + lr;
    bvl[j] = (col < VOCAB) ? bias[col] * LOG2E : -1e30f;
  }

  float sp[16];
#pragma unroll
  for (int i = 0; i < 4; ++i) {
#pragma unroll
    for (int r = 0; r < 4; ++r) {
      float s_loc = 0.f;
#pragma unroll
      for (int j = 0; j < 4; ++j)
        s_loc += exp2f(fmaf(acc[i][j][r], LOG2E, bvl[j]));
      sp[i * 4 + r] = s_loc;
    }
  }

  // stacking reduction over the 16 lanes of each quad-group:
  // ends with lane lr holding the full sum for reg index u == lr.
  float t1[8];
#pragma unroll
  for (int u = 0; u < 8; ++u) {
    float a = sp[2 * u]     + __shfl_xor(sp[2 * u],     1);
    float b = sp[2 * u + 1] + __shfl_xor(sp[2 * u + 1], 1);
    t1[u] = (lr & 1) ? b : a;
  }
  float t2[4];
#pragma unroll
  for (int u = 0; u < 4; ++u) {
    float a = t1[2 * u]     + __shfl_xor(t1[2 * u],     2);
    float b = t1[2 * u + 1] + __shfl_xor(t1[2 * u + 1], 2);
    t2[u] = (lr & 2) ? b : a;
  }
  float t3[2];
#pragma unroll
  for (int u = 0; u < 2; ++u) {
    float a = t2[2 * u]     + __shfl_xor(t2[2 * u],     4);
    float b = t2[2 * u + 1] + __shfl_xor(t2[2 * u + 1], 4);
    t3[u] = (lr & 4) ? b : a;
  }
  {
    float a = t3[0] + __shfl_xor(t3[0], 8);
    float b = t3[1] + __shfl_xor(t3[1], 8);
    float ssum = (lr & 8) ? b : a;
    const int row = rowBase + wr + (lr >> 2) * 16 + quad * 4 + (lr & 3);
    atomicAdd(&sg[row], ssum);
  }
}

// ---- final: loss = log(V+1) - mean(py/s)  (q-term ~7e-10, dropped) ----
__global__ void finalize_kernel(const float* __restrict__ sg, const float* __restrict__ py,
                                float* __restrict__ out) {
  __shared__ float red[256];
  float a = 0.f;
  for (int i = threadIdx.x; i < NROWS; i += 256)
    a += py[i] / sg[i];
  red[threadIdx.x] = a;
  __syncthreads();
  for (int st = 128; st > 0; st >>= 1) {
    if (threadIdx.x < st) red[threadIdx.x] += red[threadIdx.x + st];
    __syncthreads();
  }
  if (threadIdx.x == 0)
    out[0] = logf((float)(VOCAB + 1)) - red[0] * (1.f / (float)NROWS);
}

extern "C" void kernel_launch(void* const* d_in, const int* in_sizes, int n_in,
                              void* d_out, int out_size, void* d_ws, size_t ws_size,
                              hipStream_t stream) {
  const float* x = (const float*)d_in[0];
  const int*   y = (const int*)d_in[1];
  const float* W = (const float*)d_in[2];
  const float* b = (const float*)d_in[3];

  char* ws = (char*)d_ws;
  ushort* xb = (ushort*)ws;                               // 8,388,608 B
  ushort* wb = (ushort*)(ws + 8388608);                   // 29,753,344 B
  float*  sg = (float*)(ws + 8388608 + 29753344);         // 32 KiB
  float*  py = sg + NROWS;                                // 32 KiB

  prep_kernel<<<20704, 256, 0, stream>>>(x, W, b, y, xb, wb, py, sg);
  gemm_stats_kernel<<<dim3(64, 227), 256, 0, stream>>>(xb, wb, b, sg);
  finalize_kernel<<<1, 256, 0, stream>>>(sg, py, (float*)d_out);
}

// Round 4
// 347.067 us; speedup vs baseline: 1.3945x; 1.1053x over previous
//
#include <hip/hip_runtime.h>
#include <stdint.h>

#define VOCAB 28996
#define EMBED 512
#define NROWS 8192
#define VPAD  29056  /* 227 * 128 */
#define LOG2E 1.4426950408889634f
#define WSCALE 16.0f
#define INV_WSCALE_L2E (LOG2E / 16.0f)

typedef __attribute__((ext_vector_type(4))) int   i32x4;
typedef __attribute__((ext_vector_type(8))) int   i32x8;
typedef __attribute__((ext_vector_type(4))) float f32x4;

__device__ __forceinline__ void gload_lds16(const void* g, void* l) {
  __builtin_amdgcn_global_load_lds(
      (__attribute__((address_space(1))) const void*)g,
      (__attribute__((address_space(3))) void*)l, 16, 0, 0);
}

// pack 4 floats -> 4 x fp8 e4m3 (OCP, RNE, saturating) in one i32
__device__ __forceinline__ int pk_fp8x4(float a, float b, float c, float d) {
  int r = __builtin_amdgcn_cvt_pk_fp8_f32(a, b, 0, false);
  r = __builtin_amdgcn_cvt_pk_fp8_f32(c, d, r, true);
  return r;
}

// ---- fused prep: cvt W*16 -> fp8 (pad to VPAD), cvt x -> fp8, p_y, zero sg ----
// blocks [0,7264): W   (VPAD*512/8/256 = 7264)
// blocks [7264,9312): x (8192*512/8/256 = 2048)
// blocks [9312,11360): py (1 wave/row, 4 rows/block)
// blocks [11360,11392): zero sg
__global__ void __launch_bounds__(256)
prep_kernel(const float* __restrict__ x, const float* __restrict__ W,
            const float* __restrict__ b, const int* __restrict__ y,
            int* __restrict__ xb, int* __restrict__ wb,
            float* __restrict__ py, float* __restrict__ sg) {
  const int bid = blockIdx.x;
  if (bid < 7264) {                        // ---- cvt W*16 -> fp8 ----
    int i = (bid * 256 + threadIdx.x) * 8; // float index; VK multiple of 8
    const int VK = VOCAB * EMBED;
    int2 o;
    if (i < VK) {
      float4 v0 = *(const float4*)(W + i);
      float4 v1 = *(const float4*)(W + i + 4);
      o.x = pk_fp8x4(v0.x * WSCALE, v0.y * WSCALE, v0.z * WSCALE, v0.w * WSCALE);
      o.y = pk_fp8x4(v1.x * WSCALE, v1.y * WSCALE, v1.z * WSCALE, v1.w * WSCALE);
    } else { o.x = 0; o.y = 0; }
    *(int2*)(wb + i / 4) = o;
  } else if (bid < 9312) {                 // ---- cvt x -> fp8 ----
    int i = ((bid - 7264) * 256 + threadIdx.x) * 8;
    float4 v0 = *(const float4*)(x + i);
    float4 v1 = *(const float4*)(x + i + 4);
    int2 o;
    o.x = pk_fp8x4(v0.x, v0.y, v0.z, v0.w);
    o.y = pk_fp8x4(v1.x, v1.y, v1.z, v1.w);
    *(int2*)(xb + i / 4) = o;
  } else if (bid < 11360) {                // ---- py: e^{x.W[y]+b[y]}, fp32 exact ----
    const int row  = ((bid - 9312) * 256 + threadIdx.x) >> 6;
    const int lane = threadIdx.x & 63;
    const int yr = y[row];
    const float4* xr = (const float4*)(x + (size_t)row * EMBED);
    const float4* wr = (const float4*)(W + (size_t)yr * EMBED);
    float d = 0.f;
#pragma unroll
    for (int t = 0; t < 2; ++t) {
      float4 a = xr[lane * 2 + t], c = wr[lane * 2 + t];
      d += a.x * c.x + a.y * c.y + a.z * c.z + a.w * c.w;
    }
#pragma unroll
    for (int m = 1; m < 64; m <<= 1) d += __shfl_xor(d, m);
    if (lane == 0) py[row] = __expf(d + b[yr]);
  } else {                                 // ---- zero sg ----
    int i = (bid - 11360) * 256 + threadIdx.x;
    sg[i] = 0.f;
  }
}

// ---- fused GEMM (16*logits = x . (16W)^T, MX-fp8 K=128) + row-sum of exp ----
// 128x128 tile, BK=128 (one mfma_scale_f32_16x16x128_f8f6f4 per frag pair),
// 4 waves (2x2, each 64x64). LDS row = 128 fp8 = 128 B; 16B-chunk XOR swizzle
// (chunk J of row R at LDS[R*128 + ((J^(R&7))*16)]) keeps staging contiguous
// for global_load_lds and fragment reads bank-conflict-free.
__global__ void __launch_bounds__(256, 2)
gemm_stats_kernel(const uint8_t* __restrict__ xb, const uint8_t* __restrict__ wb,
                  const float* __restrict__ bias, float* __restrict__ sg) {
  __shared__ uint8_t lA[128 * 128];
  __shared__ uint8_t lB[128 * 128];

  const int tid  = threadIdx.x;
  const int lane = tid & 63;
  const int w    = tid >> 6;       // wave 0..3
  const int quad = lane >> 4;      // 0..3
  const int lr   = lane & 15;      // 0..15
  const int kx   = lr & 7;         // swizzle key (row&7) for fragment reads
  const int wr   = (w >> 1) * 64;  // wave row offset in tile
  const int wc   = (w & 1) * 64;   // wave col offset in tile
  const int rowBase = blockIdx.x * 128;  // x rows (grid.x = 64)
  const int colBase = blockIdx.y * 128;  // vocab cols (grid.y = 227)

  f32x4 acc[4][4];
#pragma unroll
  for (int i = 0; i < 4; ++i)
#pragma unroll
    for (int j = 0; j < 4; ++j) {
      f32x4 z = {0.f, 0.f, 0.f, 0.f};
      acc[i][j] = z;
    }

  const int srow = lane >> 3;                    // 0..7 (row within 8-row chunk)
  const int skel = ((lane & 7) ^ srow) * 16;     // swizzled byte offset in row

  for (int kt = 0; kt < 4; ++kt) {
    const int k0 = kt * 128;                     // byte offset in 512B row
#pragma unroll
    for (int t = 0; t < 4; ++t) {
      const int c = w * 4 + t;                   // chunk 0..15 (8 rows each)
      const int r = c * 8 + srow;                // tile row 0..127
      gload_lds16(xb + (size_t)(rowBase + r) * EMBED + k0 + skel, &lA[c * 1024]);
      gload_lds16(wb + (size_t)(colBase + r) * EMBED + k0 + skel, &lB[c * 1024]);
    }
    __syncthreads();
    {
      // fragment: lane holds 32 contiguous k-bytes at k = quad*32 (chunks 2q,2q+1)
      const int cLo = ((2 * quad)     ^ kx) * 16;
      const int cHi = ((2 * quad + 1) ^ kx) * 16;
      i32x8 af[4], bq[4];
#pragma unroll
      for (int i = 0; i < 4; ++i) {
        const int base = (wr + i * 16 + lr) * 128;
        i32x4 lo = *(const i32x4*)&lA[base + cLo];
        i32x4 hi = *(const i32x4*)&lA[base + cHi];
        af[i] = __builtin_shufflevector(lo, hi, 0, 1, 2, 3, 4, 5, 6, 7);
      }
#pragma unroll
      for (int j = 0; j < 4; ++j) {
        const int base = (wc + j * 16 + lr) * 128;
        i32x4 lo = *(const i32x4*)&lB[base + cLo];
        i32x4 hi = *(const i32x4*)&lB[base + cHi];
        bq[j] = __builtin_shufflevector(lo, hi, 0, 1, 2, 3, 4, 5, 6, 7);
      }
#pragma unroll
      for (int i = 0; i < 4; ++i)
#pragma unroll
        for (int j = 0; j < 4; ++j)
          acc[i][j] = __builtin_amdgcn_mfma_scale_f32_16x16x128_f8f6f4(
              af[i], bq[j], acc[i][j], 0, 0,            // cbsz=fp8, blgp=fp8
              0, 0x7F7F7F7F, 0, 0x7F7F7F7F);            // scales = 2^0
    }
    __syncthreads();
  }

  // ---- epilogue: s_row += sum_j exp(acc/16 + bias) ----
  // C/D layout (shape-determined): col = lane&15, row = quad*4 + reg
  float bvl[4];
#pragma unroll
  for (int j = 0; j < 4; ++j) {
    const int col = colBase + wc + j * 16 + lr;
    bvl[j] = (col < VOCAB) ? bias[col] * LOG2E : -1e30f;
  }

  float sp[16];
#pragma unroll
  for (int i = 0; i < 4; ++i)
#pragma unroll
    for (int r = 0; r < 4; ++r) {
      float s_loc = 0.f;
#pragma unroll
      for (int j = 0; j < 4; ++j)
        s_loc += exp2f(fmaf(acc[i][j][r], INV_WSCALE_L2E, bvl[j]));
      sp[i * 4 + r] = s_loc;
    }

  // stacking reduction over the 16 lanes of each quad-group:
  // ends with lane lr holding the full sum for reg index u == lr.
  float t1[8];
#pragma unroll
  for (int u = 0; u < 8; ++u) {
    float a = sp[2 * u]     + __shfl_xor(sp[2 * u],     1);
    float b = sp[2 * u + 1] + __shfl_xor(sp[2 * u + 1], 1);
    t1[u] = (lr & 1) ? b : a;
  }
  float t2[4];
#pragma unroll
  for (int u = 0; u < 4; ++u) {
    float a = t1[2 * u]     + __shfl_xor(t1[2 * u],     2);
    float b = t1[2 * u + 1] + __shfl_xor(t1[2 * u + 1], 2);
    t2[u] = (lr & 2) ? b : a;
  }
  float t3[2];
#pragma unroll
  for (int u = 0; u < 2; ++u) {
    float a = t2[2 * u]     + __shfl_xor(t2[2 * u],     4);
    float b = t2[2 * u + 1] + __shfl_xor(t2[2 * u + 1], 4);
    t3[u] = (lr & 4) ? b : a;
  }
  {
    float a = t3[0] + __shfl_xor(t3[0], 8);
    float b = t3[1] + __shfl_xor(t3[1], 8);
    float ssum = (lr & 8) ? b : a;
    const int row = rowBase + wr + (lr >> 2) * 16 + quad * 4 + (lr & 3);
    atomicAdd(&sg[row], ssum);
  }
}

// ---- final: loss = log(V+1) - mean(py/s)  (q-term ~7e-10, dropped) ----
__global__ void finalize_kernel(const float* __restrict__ sg, const float* __restrict__ py,
                                float* __restrict__ out) {
  __shared__ float red[256];
  float a = 0.f;
  for (int i = threadIdx.x; i < NROWS; i += 256)
    a += py[i] / sg[i];
  red[threadIdx.x] = a;
  __syncthreads();
  for (int st = 128; st > 0; st >>= 1) {
    if (threadIdx.x < st) red[threadIdx.x] += red[threadIdx.x + st];
    __syncthreads();
  }
  if (threadIdx.x == 0)
    out[0] = logf((float)(VOCAB + 1)) - red[0] * (1.f / (float)NROWS);
}

extern "C" void kernel_launch(void* const* d_in, const int* in_sizes, int n_in,
                              void* d_out, int out_size, void* d_ws, size_t ws_size,
                              hipStream_t stream) {
  const float* x = (const float*)d_in[0];
  const int*   y = (const int*)d_in[1];
  const float* W = (const float*)d_in[2];
  const float* b = (const float*)d_in[3];

  char* ws = (char*)d_ws;
  uint8_t* xb = (uint8_t*)ws;                             // 4,194,304 B
  uint8_t* wb = (uint8_t*)(ws + 4194304);                 // 14,876,672 B
  float*   sg = (float*)(ws + 4194304 + 14876672);        // 32 KiB
  float*   py = sg + NROWS;                               // 32 KiB

  prep_kernel<<<11392, 256, 0, stream>>>(x, W, b, y, (int*)xb, (int*)wb, py, sg);
  gemm_stats_kernel<<<dim3(64, 227), 256, 0, stream>>>(xb, wb, b, sg);
  finalize_kernel<<<1, 256, 0, stream>>>(sg, py, (float*)d_out);
}

// Round 5
// 269.572 us; speedup vs baseline: 1.7954x; 1.2875x over previous
//
#include <hip/hip_runtime.h>
#include <stdint.h>

#define VOCAB 28996
#define EMBED 512
#define NROWS 8192
#define VPAD  29056  /* 227 * 128 */
#define LOG2E 1.4426950408889634f
#define WSCALE 16.0f
#define INV_WSCALE_L2E (LOG2E / 16.0f)

typedef __attribute__((ext_vector_type(4)))  int   i32x4;
typedef __attribute__((ext_vector_type(8)))  int   i32x8;
typedef __attribute__((ext_vector_type(16))) float f32x16;

__device__ __forceinline__ void gload_lds16(const void* g, void* l) {
  __builtin_amdgcn_global_load_lds(
      (__attribute__((address_space(1))) const void*)g,
      (__attribute__((address_space(3))) void*)l, 16, 0, 0);
}

// pack 4 floats -> 4 x fp8 e4m3 (OCP, RNE, saturating) in one i32
__device__ __forceinline__ int pk_fp8x4(float a, float b, float c, float d) {
  int r = __builtin_amdgcn_cvt_pk_fp8_f32(a, b, 0, false);
  r = __builtin_amdgcn_cvt_pk_fp8_f32(c, d, r, true);
  return r;
}

// ---- fused prep: cvt W*16 -> fp8 (pad to VPAD), cvt x -> fp8, p_y, zero sg ----
// blocks [0,7264): W   (VPAD*512/8/256 = 7264)
// blocks [7264,9312): x (8192*512/8/256 = 2048)
// blocks [9312,11360): py (1 wave/row, 4 rows/block)
// blocks [11360,11392): zero sg
__global__ void __launch_bounds__(256)
prep_kernel(const float* __restrict__ x, const float* __restrict__ W,
            const float* __restrict__ b, const int* __restrict__ y,
            int* __restrict__ xb, int* __restrict__ wb,
            float* __restrict__ py, float* __restrict__ sg) {
  const int bid = blockIdx.x;
  if (bid < 7264) {                        // ---- cvt W*16 -> fp8 ----
    int i = (bid * 256 + threadIdx.x) * 8; // float index; VK multiple of 8
    const int VK = VOCAB * EMBED;
    int2 o;
    if (i < VK) {
      float4 v0 = *(const float4*)(W + i);
      float4 v1 = *(const float4*)(W + i + 4);
      o.x = pk_fp8x4(v0.x * WSCALE, v0.y * WSCALE, v0.z * WSCALE, v0.w * WSCALE);
      o.y = pk_fp8x4(v1.x * WSCALE, v1.y * WSCALE, v1.z * WSCALE, v1.w * WSCALE);
    } else { o.x = 0; o.y = 0; }
    *(int2*)(wb + i / 4) = o;
  } else if (bid < 9312) {                 // ---- cvt x -> fp8 ----
    int i = ((bid - 7264) * 256 + threadIdx.x) * 8;
    float4 v0 = *(const float4*)(x + i);
    float4 v1 = *(const float4*)(x + i + 4);
    int2 o;
    o.x = pk_fp8x4(v0.x, v0.y, v0.z, v0.w);
    o.y = pk_fp8x4(v1.x, v1.y, v1.z, v1.w);
    *(int2*)(xb + i / 4) = o;
  } else if (bid < 11360) {                // ---- py: e^{x.W[y]+b[y]}, fp32 exact ----
    const int row  = ((bid - 9312) * 256 + threadIdx.x) >> 6;
    const int lane = threadIdx.x & 63;
    const int yr = y[row];
    const float4* xr = (const float4*)(x + (size_t)row * EMBED);
    const float4* wr = (const float4*)(W + (size_t)yr * EMBED);
    float d = 0.f;
#pragma unroll
    for (int t = 0; t < 2; ++t) {
      float4 a = xr[lane * 2 + t], c = wr[lane * 2 + t];
      d += a.x * c.x + a.y * c.y + a.z * c.z + a.w * c.w;
    }
#pragma unroll
    for (int m = 1; m < 64; m <<= 1) d += __shfl_xor(d, m);
    if (lane == 0) py[row] = __expf(d + b[yr]);
  } else {                                 // ---- zero sg ----
    int i = (bid - 11360) * 256 + threadIdx.x;
    sg[i] = 0.f;
  }
}

// ---- fused GEMM (16*logits = x . (16W)^T, MX-fp8 32x32x64) + row-sum exp ----
// 128x128 tile, BK=128 staged; 4 waves 2x2, each wave 64x64 = 2x2 of 32x32.
// Low register pressure: per kk only bq[2]+af live (24 VGPRs) + 64 acc ->
// fits the 128-reg budget of launch_bounds(256,4) = 4 waves/SIMD, no spills.
// LDS row = 128 B; 16B-chunk XOR swizzle (chunk J of row R at
// LDS[R*128 + ((J^(R&7))*16)]) — staging contiguous for global_load_lds,
// fragment reads hit all 32 banks per 8-lane phase (conflict-free).
__global__ void __launch_bounds__(256, 4)
gemm_stats_kernel(const uint8_t* __restrict__ xb, const uint8_t* __restrict__ wb,
                  const float* __restrict__ bias, float* __restrict__ sg) {
  __shared__ uint8_t lA[128 * 128];
  __shared__ uint8_t lB[128 * 128];

  const int tid  = threadIdx.x;
  const int lane = tid & 63;
  const int w    = tid >> 6;       // wave 0..3
  const int l31  = lane & 31;
  const int h    = lane >> 5;      // k-half for 32x32 operands
  const int kx   = lane & 7;       // swizzle key (fragment row & 7 == lane & 7)
  const int wr   = (w >> 1) * 64;  // wave row offset in tile
  const int wc   = (w & 1) * 64;   // wave col offset in tile
  const int rowBase = blockIdx.x * 128;  // x rows (grid.x = 64)
  const int colBase = blockIdx.y * 128;  // vocab cols (grid.y = 227)

  f32x16 acc[2][2];
#pragma unroll
  for (int i = 0; i < 2; ++i)
#pragma unroll
    for (int j = 0; j < 2; ++j)
#pragma unroll
      for (int r = 0; r < 16; ++r) acc[i][j][r] = 0.f;

  const int srow = lane >> 3;                    // 0..7 (row within 8-row chunk)
  const int skel = ((lane & 7) ^ srow) * 16;     // swizzled byte offset in row

  const int aBase = (wr + l31) * 128;            // ii=0 fragment row base
  const int bBase = (wc + l31) * 128;            // jj=0 fragment row base

  for (int kt = 0; kt < 4; ++kt) {
    const int k0 = kt * 128;                     // byte offset in 512B row
#pragma unroll
    for (int t = 0; t < 4; ++t) {
      const int c = w * 4 + t;                   // chunk 0..15 (8 rows each)
      const int r = c * 8 + srow;                // tile row 0..127
      gload_lds16(xb + (size_t)(rowBase + r) * EMBED + k0 + skel, &lA[c * 1024]);
      gload_lds16(wb + (size_t)(colBase + r) * EMBED + k0 + skel, &lB[c * 1024]);
    }
    __syncthreads();
#pragma unroll
    for (int kk = 0; kk < 2; ++kk) {
      // lane's 32 k-bytes: chunks J0, J0+1 where J0 = kk*4 + h*2 (even)
      const int c0 = ((kk * 4 + h * 2) ^ kx) << 4;
      const int c1 = c0 ^ 16;                    // ((J0|1)^kx)*16
      i32x8 bq[2];
#pragma unroll
      for (int jj = 0; jj < 2; ++jj) {
        const int base = bBase + jj * 32 * 128;
        i32x4 lo = *(const i32x4*)&lB[base + c0];
        i32x4 hi = *(const i32x4*)&lB[base + c1];
        bq[jj] = __builtin_shufflevector(lo, hi, 0, 1, 2, 3, 4, 5, 6, 7);
      }
#pragma unroll
      for (int ii = 0; ii < 2; ++ii) {
        const int base = aBase + ii * 32 * 128;
        i32x4 lo = *(const i32x4*)&lA[base + c0];
        i32x4 hi = *(const i32x4*)&lA[base + c1];
        i32x8 af = __builtin_shufflevector(lo, hi, 0, 1, 2, 3, 4, 5, 6, 7);
        acc[ii][0] = __builtin_amdgcn_mfma_scale_f32_32x32x64_f8f6f4(
            af, bq[0], acc[ii][0], 0, 0, 0, 0x7F7F7F7F, 0, 0x7F7F7F7F);
        acc[ii][1] = __builtin_amdgcn_mfma_scale_f32_32x32x64_f8f6f4(
            af, bq[1], acc[ii][1], 0, 0, 0, 0x7F7F7F7F, 0, 0x7F7F7F7F);
      }
    }
    __syncthreads();
  }

  // ---- epilogue: s_row += sum_j exp(acc/16 + bias) ----
  // 32x32 C/D layout (m74/m101): col = lane&31, row = (reg&3)+8*(reg>>2)+4*h
  float bvl[2];
#pragma unroll
  for (int jj = 0; jj < 2; ++jj) {
    const int col = colBase + wc + jj * 32 + l31;
    bvl[jj] = (col < VOCAB) ? bias[col] * LOG2E : -1e30f;
  }

  float sp[32];  // v = ii*16 + reg
#pragma unroll
  for (int ii = 0; ii < 2; ++ii)
#pragma unroll
    for (int r = 0; r < 16; ++r)
      sp[ii * 16 + r] = exp2f(fmaf(acc[ii][0][r], INV_WSCALE_L2E, bvl[0])) +
                        exp2f(fmaf(acc[ii][1][r], INV_WSCALE_L2E, bvl[1]));

  // stacking reduction over the 32 cols (xor 1..16 stays within the h-half);
  // ends with lane holding the full col-sum for value index v == (lane&31).
  float t1[16];
#pragma unroll
  for (int u = 0; u < 16; ++u) {
    float a = sp[2 * u]     + __shfl_xor(sp[2 * u],     1);
    float b = sp[2 * u + 1] + __shfl_xor(sp[2 * u + 1], 1);
    t1[u] = (l31 & 1) ? b : a;
  }
  float t2[8];
#pragma unroll
  for (int u = 0; u < 8; ++u) {
    float a = t1[2 * u]     + __shfl_xor(t1[2 * u],     2);
    float b = t1[2 * u + 1] + __shfl_xor(t1[2 * u + 1], 2);
    t2[u] = (l31 & 2) ? b : a;
  }
  float t3[4];
#pragma unroll
  for (int u = 0; u < 4; ++u) {
    float a = t2[2 * u]     + __shfl_xor(t2[2 * u],     4);
    float b = t2[2 * u + 1] + __shfl_xor(t2[2 * u + 1], 4);
    t3[u] = (l31 & 4) ? b : a;
  }
  float t4[2];
#pragma unroll
  for (int u = 0; u < 2; ++u) {
    float a = t3[2 * u]     + __shfl_xor(t3[2 * u],     8);
    float b = t3[2 * u + 1] + __shfl_xor(t3[2 * u + 1], 8);
    t4[u] = (l31 & 8) ? b : a;
  }
  {
    float a = t4[0] + __shfl_xor(t4[0], 16);
    float b = t4[1] + __shfl_xor(t4[1], 16);
    float ssum = (l31 & 16) ? b : a;
    const int v = l31;                 // ii = v>>4, reg = v&15
    const int row = rowBase + wr + (v >> 4) * 32 + (v & 3) + 8 * ((v & 15) >> 2) + 4 * h;
    atomicAdd(&sg[row], ssum);
  }
}

// ---- final: loss = log(V+1) - mean(py/s)  (q-term ~7e-10, dropped) ----
__global__ void finalize_kernel(const float* __restrict__ sg, const float* __restrict__ py,
                                float* __restrict__ out) {
  __shared__ float red[256];
  float a = 0.f;
  for (int i = threadIdx.x; i < NROWS; i += 256)
    a += py[i] / sg[i];
  red[threadIdx.x] = a;
  __syncthreads();
  for (int st = 128; st > 0; st >>= 1) {
    if (threadIdx.x < st) red[threadIdx.x] += red[threadIdx.x + st];
    __syncthreads();
  }
  if (threadIdx.x == 0)
    out[0] = logf((float)(VOCAB + 1)) - red[0] * (1.f / (float)NROWS);
}

extern "C" void kernel_launch(void* const* d_in, const int* in_sizes, int n_in,
                              void* d_out, int out_size, void* d_ws, size_t ws_size,
                              hipStream_t stream) {
  const float* x = (const float*)d_in[0];
  const int*   y = (const int*)d_in[1];
  const float* W = (const float*)d_in[2];
  const float* b = (const float*)d_in[3];

  char* ws = (char*)d_ws;
  uint8_t* xb = (uint8_t*)ws;                             // 4,194,304 B
  uint8_t* wb = (uint8_t*)(ws + 4194304);                 // 14,876,672 B
  float*   sg = (float*)(ws + 4194304 + 14876672);        // 32 KiB
  float*   py = sg + NROWS;                               // 32 KiB

  prep_kernel<<<11392, 256, 0, stream>>>(x, W, b, y, (int*)xb, (int*)wb, py, sg);
  gemm_stats_kernel<<<dim3(64, 227), 256, 0, stream>>>(xb, wb, b, sg);
  finalize_kernel<<<1, 256, 0, stream>>>(sg, py, (float*)d_out);
}